// Round 3
// baseline (492.181 us; speedup 1.0000x reference)
//
#include <hip/hip_runtime.h>

// Walsh-Hadamard, N = 2^25 fp32. Two passes (stages commute):
//   pass1: bits 0..13 within contiguous 2^14 tiles
//   pass2: bits 14..24 = column transform of a (2048 x 2^14) matrix view
// pass2: 256 thr x 32 float4 (block = 2048 rows x 4 f4-cols), 32 KiB LDS,
// all-lane quarter-round exchanges keyed on (r10,r9) which stay in regs
// across both exchanges. 4 blocks/CU resident -> global/LDS phases overlap.

// clang's nontemporal builtins reject HIP_vector_type -> go through a
// native ext_vector_type alias (bit-identical layout).
typedef float vf4 __attribute__((ext_vector_type(4)));

__device__ __forceinline__ float4 ntload(const float4* p) {
  vf4 r = __builtin_nontemporal_load(reinterpret_cast<const vf4*>(p));
  return *reinterpret_cast<float4*>(&r);
}
__device__ __forceinline__ void ntstore(float4* p, float4 v) {
  __builtin_nontemporal_store(*reinterpret_cast<vf4*>(&v),
                              reinterpret_cast<vf4*>(p));
}

__device__ __forceinline__ void bfly(float4& a, float4& b) {
  float ax = a.x, ay = a.y, az = a.z, aw = a.w;
  a.x = ax + b.x; a.y = ay + b.y; a.z = az + b.z; a.w = aw + b.w;
  b.x = ax - b.x; b.y = ay - b.y; b.z = az - b.z; b.w = aw - b.w;
}

// 4 butterfly stages across the 4 index bits of v[16]
__device__ __forceinline__ void cross4(float4 (&v)[16]) {
#pragma unroll
  for (int m = 0; m < 4; ++m) {
#pragma unroll
    for (int k = 0; k < 16; ++k) {
      if (!(k & (1 << m))) bfly(v[k], v[k | (1 << m)]);
    }
  }
}

// ---------------- pass 1: bits 0..13 ----------------
// tile = 2^14 floats, 256 threads, 16 float4/thread, 64 KiB LDS.
// LDS float4-index swizzle: L(q) = q ^ ((q>>4)&15) -> conflict-free.
// Loads nontemporal: x is read exactly once.
__global__ __launch_bounds__(256) void wht_pass1(const float4* __restrict__ in4,
                                                 float4* __restrict__ out4) {
  __shared__ float4 lds[4096];  // 64 KiB
  const int t = threadIdx.x;
  const int base4 = (int)blockIdx.x << 12;  // tile base in float4s
  float4 v[16];
#pragma unroll
  for (int k = 0; k < 16; ++k)
    v[k] = ntload(&in4[base4 + t + (k << 8)]);
  // bits 0 and 1 (inside each float4)
#pragma unroll
  for (int k = 0; k < 16; ++k) {
    float4 a = v[k];
    float s0 = a.x + a.y, d0 = a.x - a.y, s1 = a.z + a.w, d1 = a.z - a.w;
    v[k].x = s0 + s1; v[k].y = d0 + d1; v[k].z = s0 - s1; v[k].w = d0 - d1;
  }
  cross4(v);  // bits 10..13 (k = e[13:10])

  // exchange 1: -> thread holds u = e[5:2]
#pragma unroll
  for (int k = 0; k < 16; ++k) { int q = t + (k << 8); lds[q ^ ((q >> 4) & 15)] = v[k]; }
  __syncthreads();
#pragma unroll
  for (int u = 0; u < 16; ++u) { int q = u + (t << 4); v[u] = lds[q ^ ((q >> 4) & 15)]; }
  cross4(v);  // bits 2..5

  // exchange 2: write set == own read set -> no barrier needed before writes
#pragma unroll
  for (int u = 0; u < 16; ++u) { int q = u + (t << 4); lds[q ^ ((q >> 4) & 15)] = v[u]; }
  __syncthreads();
  const int c0 = t & 15, c1 = t >> 4;
#pragma unroll
  for (int u = 0; u < 16; ++u) {
    int q = c0 + (u << 4) + (c1 << 8);
    v[u] = lds[q ^ ((q >> 4) & 15)];
  }
  cross4(v);  // bits 6..9 (u = e[9:6])

#pragma unroll
  for (int u = 0; u < 16; ++u) out4[base4 + c0 + (u << 4) + (c1 << 8)] = v[u];
}

// ---------------- pass 2: bits 14..24 ----------------
// Matrix view: 2048 rows (idx>>14) x 2^12 float4-cols. Block = 4 f4-cols x
// all rows = 128 KiB data; 256 threads x 32 float4. LDS = 32 KiB = one
// (r10,r9) slice; exchanges run as 4 all-lane quarter-rounds (r10,r9 are
// reg bits in ALL THREE layouts, so every lane is active every round).
// Bit schedule: cross5 r6..r10 (regs k) | E1 -> cross3 r0..r2 | E2 ->
// cross3 r3..r5. Layouts: A regs {r10,r9,r8,r7,r6}, B regs {r10,r9,r2,r1,r0},
// C regs {r10,r9,r5,r4,r3}.
// LDS slot s = (r[8:0] & 511)*4 + c4, swizzle s ^= (s>>5)&7: all four
// ds patterns are exactly 8 lanes per 4-bank group -> conflict-free.
__global__ __launch_bounds__(256, 4) void wht_pass2(float4* __restrict__ b4) {
  __shared__ float4 lds[2048];  // 32 KiB
  const int t = threadIdx.x;
  const int cb4 = (int)blockIdx.x << 2;  // column base in float4s (16 cols)
  const int c4 = t & 3;                  // float4-col within block
  const int rA = t >> 2;                 // layout A: r[5:0]; layout B: r[8:3]
  float4 v[32];
#pragma unroll
  for (int k = 0; k < 32; ++k)
    v[k] = ntload(&b4[((rA + (k << 6)) << 12) + cb4 + c4]);

  // cross row bits 6..10 (k bits 0..4)
#pragma unroll
  for (int m = 0; m < 5; ++m) {
#pragma unroll
    for (int k = 0; k < 32; ++k)
      if (!(k & (1 << m))) bfly(v[k], v[k | (1 << m)]);
  }

  // exchange 1: regs {r10,r9 | r8,r7,r6} -> {r10,r9 | r2,r1,r0}
  // quarter-round q = (r10<<1)|r9; reg ids for slice q: RQ|m, RQ=(q&1)<<3|(q>>1)<<4.
#pragma unroll
  for (int q = 0; q < 4; ++q) {
    const int RQ = ((q & 1) << 3) | ((q >> 1) << 4);
    if (q) __syncthreads();
#pragma unroll
    for (int m = 0; m < 8; ++m) {  // m = r[8:6]
      int s = ((rA + (m << 6)) << 2) | c4;
      lds[s ^ ((s >> 5) & 7)] = v[RQ | m];
    }
    __syncthreads();
#pragma unroll
    for (int jm = 0; jm < 8; ++jm) {  // jm = r[2:0]; thread now r[8:3]=rA
      int s = ((jm + (rA << 3)) << 2) | c4;
      v[RQ | jm] = lds[s ^ ((s >> 5) & 7)];
    }
  }
  // cross row bits 0..2 (reg bits 0..2)
#pragma unroll
  for (int m = 0; m < 3; ++m) {
#pragma unroll
    for (int k = 0; k < 32; ++k)
      if (!(k & (1 << m))) bfly(v[k], v[k | (1 << m)]);
  }

  // exchange 2: regs {r10,r9 | r2,r1,r0} -> {r10,r9 | r5,r4,r3}
  const int rlowC = (t >> 2) & 7;  // r[2:0] in layout C
  const int rmidC = t >> 5;        // r[8:6] in layout C
#pragma unroll
  for (int q = 0; q < 4; ++q) {
    const int RQ = ((q & 1) << 3) | ((q >> 1) << 4);
    __syncthreads();  // prior round's reads (or E1 round 3) still in flight
#pragma unroll
    for (int jm = 0; jm < 8; ++jm) {  // write own E1-read addresses
      int s = ((jm + (rA << 3)) << 2) | c4;
      lds[s ^ ((s >> 5) & 7)] = v[RQ | jm];
    }
    __syncthreads();
#pragma unroll
    for (int im = 0; im < 8; ++im) {  // im = r[5:3]
      int s = ((rlowC + (im << 3) + (rmidC << 6)) << 2) | c4;
      v[RQ | im] = lds[s ^ ((s >> 5) & 7)];
    }
  }
  // cross row bits 3..5 (reg bits 0..2)
#pragma unroll
  for (int m = 0; m < 3; ++m) {
#pragma unroll
    for (int k = 0; k < 32; ++k)
      if (!(k & (1 << m))) bfly(v[k], v[k | (1 << m)]);
  }

  // store: row = rlowC | im<<3 | rmidC<<6 | r9<<9 | r10<<10.
  // Per instr: 16 rows x 64 B contiguous. Nontemporal: never re-read on GPU.
#pragma unroll
  for (int i = 0; i < 32; ++i) {
    int row = rlowC + ((i & 7) << 3) + (rmidC << 6) + (((i >> 3) & 1) << 9) +
              ((i >> 4) << 10);
    ntstore(&b4[(row << 12) + cb4 + c4], v[i]);
  }
}

extern "C" void kernel_launch(void* const* d_in, const int* in_sizes, int n_in,
                              void* d_out, int out_size, void* d_ws, size_t ws_size,
                              hipStream_t stream) {
  (void)in_sizes; (void)n_in; (void)d_ws; (void)ws_size; (void)out_size;
  const float* x = (const float*)d_in[0];
  float* out = (float*)d_out;
  // pass1: 2^25 / 2^14 = 2048 tiles
  wht_pass1<<<2048, 256, 0, stream>>>((const float4*)x, (float4*)out);
  // pass2: 2^12 f4-cols / 4 = 1024 tiles, in-place on d_out
  wht_pass2<<<1024, 256, 0, stream>>>((float4*)out);
}

// Round 4
// 417.809 us; speedup vs baseline: 1.1780x; 1.1780x over previous
//
#include <hip/hip_runtime.h>

// Walsh-Hadamard, N = 2^25 fp32. Two passes (stages commute):
//   pass1: bits 0..13 within contiguous 2^14 tiles
//   pass2: bits 14..24 = column transform of a (2048 x 2^14) matrix view
// pass2: 512 thr x 32 float4, block = 2048 rows x 8 f4-cols (128-B row
// segments -> no HBM read/write amplification), LDS = 64 KiB = one
// (r10,r9) quarter-slice -> 2 blocks/CU. Exchanges are 4 all-lane
// quarter-rounds keyed on (r10,r9), which stay register-resident in all
// three data layouts.

// clang's nontemporal builtins reject HIP_vector_type -> go through a
// native ext_vector_type alias (bit-identical layout).
typedef float vf4 __attribute__((ext_vector_type(4)));

__device__ __forceinline__ float4 ntload(const float4* p) {
  vf4 r = __builtin_nontemporal_load(reinterpret_cast<const vf4*>(p));
  return *reinterpret_cast<float4*>(&r);
}
__device__ __forceinline__ void ntstore(float4* p, float4 v) {
  __builtin_nontemporal_store(*reinterpret_cast<vf4*>(&v),
                              reinterpret_cast<vf4*>(p));
}

__device__ __forceinline__ void bfly(float4& a, float4& b) {
  float ax = a.x, ay = a.y, az = a.z, aw = a.w;
  a.x = ax + b.x; a.y = ay + b.y; a.z = az + b.z; a.w = aw + b.w;
  b.x = ax - b.x; b.y = ay - b.y; b.z = az - b.z; b.w = aw - b.w;
}

// 4 butterfly stages across the 4 index bits of v[16]
__device__ __forceinline__ void cross4(float4 (&v)[16]) {
#pragma unroll
  for (int m = 0; m < 4; ++m) {
#pragma unroll
    for (int k = 0; k < 16; ++k) {
      if (!(k & (1 << m))) bfly(v[k], v[k | (1 << m)]);
    }
  }
}

// ---------------- pass 1: bits 0..13 ----------------
// tile = 2^14 floats, 256 threads, 16 float4/thread, 64 KiB LDS.
// LDS float4-index swizzle: L(q) = q ^ ((q>>4)&15) -> conflict-free.
// Loads nontemporal: x is read exactly once; keep L3 for the intermediate.
__global__ __launch_bounds__(256) void wht_pass1(const float4* __restrict__ in4,
                                                 float4* __restrict__ out4) {
  __shared__ float4 lds[4096];  // 64 KiB
  const int t = threadIdx.x;
  const int base4 = (int)blockIdx.x << 12;  // tile base in float4s
  float4 v[16];
#pragma unroll
  for (int k = 0; k < 16; ++k)
    v[k] = ntload(&in4[base4 + t + (k << 8)]);
  // bits 0 and 1 (inside each float4)
#pragma unroll
  for (int k = 0; k < 16; ++k) {
    float4 a = v[k];
    float s0 = a.x + a.y, d0 = a.x - a.y, s1 = a.z + a.w, d1 = a.z - a.w;
    v[k].x = s0 + s1; v[k].y = d0 + d1; v[k].z = s0 - s1; v[k].w = d0 - d1;
  }
  cross4(v);  // bits 10..13 (k = e[13:10])

  // exchange 1: -> thread holds u = e[5:2]
#pragma unroll
  for (int k = 0; k < 16; ++k) { int q = t + (k << 8); lds[q ^ ((q >> 4) & 15)] = v[k]; }
  __syncthreads();
#pragma unroll
  for (int u = 0; u < 16; ++u) { int q = u + (t << 4); v[u] = lds[q ^ ((q >> 4) & 15)]; }
  cross4(v);  // bits 2..5

  // exchange 2: write set == own read set -> no barrier needed before writes
#pragma unroll
  for (int u = 0; u < 16; ++u) { int q = u + (t << 4); lds[q ^ ((q >> 4) & 15)] = v[u]; }
  __syncthreads();
  const int c0 = t & 15, c1 = t >> 4;
#pragma unroll
  for (int u = 0; u < 16; ++u) {
    int q = c0 + (u << 4) + (c1 << 8);
    v[u] = lds[q ^ ((q >> 4) & 15)];
  }
  cross4(v);  // bits 6..9 (u = e[9:6])

#pragma unroll
  for (int u = 0; u < 16; ++u) out4[base4 + c0 + (u << 4) + (c1 << 8)] = v[u];
}

// ---------------- pass 2: bits 14..24 ----------------
// Matrix view: 2048 rows (idx>>14) x 2^12 float4-cols. Block = 8 f4-cols x
// all 2048 rows (256 KiB data); 512 threads x 32 float4. LDS = 64 KiB =
// one (r10,r9) quarter-slice (512 rows x 8 f4). Quarter q = (r10<<1)|r9 is
// reg-id bits [4:3] in ALL THREE layouts -> every lane active every round.
// Layouts: A regs {r10,r9 | r8,r7,r6}, thread r[5:0]=t>>3, c4=t&7
//          B regs {r10,r9 | r2,r1,r0}, thread r[8:3]=t>>3
//          C regs {r10,r9 | r5,r4,r3}, thread r[2:0]=(t>>3)&7, r[8:6]=t>>6
// Bit schedule: cross5 r6..r10 | E1 -> cross3 r0..r2 | E2 -> cross3 r3..r5.
// LDS slot s = r[8:0]*8 + c4 (f4 units): same bank structure as the
// measured-conflict-free round-2 layout (~2 cyc/instr).
__global__ __launch_bounds__(512, 4) void wht_pass2(float4* __restrict__ b4) {
  __shared__ float4 lds[4096];  // 64 KiB
  const int t = threadIdx.x;
  const int cb4 = (int)blockIdx.x << 3;  // column base in float4s (32 cols)
  const int c4 = t & 7;                  // f4-col within block (128-B rows)
  const int rA = t >> 3;                 // layout A: r[5:0]; layout B: r[8:3]
  float4 v[32];
#pragma unroll
  for (int k = 0; k < 32; ++k)
    v[k] = b4[((rA + (k << 6)) << 12) + cb4 + c4];  // plain: want L3 hits

  // cross row bits 6..10 (reg bits 0..4)
#pragma unroll
  for (int m = 0; m < 5; ++m) {
#pragma unroll
    for (int k = 0; k < 32; ++k)
      if (!(k & (1 << m))) bfly(v[k], v[k | (1 << m)]);
  }

  // exchange 1: quarter-rounds q = r[10:9] = reg id >> 3.
  // write canonical slot r[8:0] = rA | m<<6; read r[8:0] = jm | rA<<3.
#pragma unroll
  for (int q = 0; q < 4; ++q) {
    const int RQ = q << 3;
    if (q) __syncthreads();  // next round's writes vs prior round's reads
#pragma unroll
    for (int m = 0; m < 8; ++m)  // m = r[8:6]
      lds[((rA + (m << 6)) << 3) + c4] = v[RQ | m];
    __syncthreads();
#pragma unroll
    for (int jm = 0; jm < 8; ++jm)  // jm = r[2:0]
      v[RQ | jm] = lds[((jm + (rA << 3)) << 3) + c4];
  }
  // cross row bits 0..2 (reg bits 0..2)
#pragma unroll
  for (int m = 0; m < 3; ++m) {
#pragma unroll
    for (int k = 0; k < 32; ++k)
      if (!(k & (1 << m))) bfly(v[k], v[k | (1 << m)]);
  }

  // exchange 2: write own E1-read slots (no barrier needed before round 0's
  // writes: each slot's E1 reader == its E2 writer). Read layout C.
  const int rlowC = (t >> 3) & 7;  // r[2:0]
  const int rmidC = t >> 6;        // r[8:6]
#pragma unroll
  for (int q = 0; q < 4; ++q) {
    const int RQ = q << 3;
    if (q) __syncthreads();  // this round's writes vs prior round's C-reads
#pragma unroll
    for (int jm = 0; jm < 8; ++jm)
      lds[((jm + (rA << 3)) << 3) + c4] = v[RQ | jm];
    __syncthreads();
#pragma unroll
    for (int im = 0; im < 8; ++im)  // im = r[5:3]
      v[RQ | im] = lds[((rlowC + (im << 3) + (rmidC << 6)) << 3) + c4];
  }
  // cross row bits 3..5 (reg bits 0..2)
#pragma unroll
  for (int m = 0; m < 3; ++m) {
#pragma unroll
    for (int k = 0; k < 32; ++k)
      if (!(k & (1 << m))) bfly(v[k], v[k | (1 << m)]);
  }

  // store: reg i = q<<3 | im; row = rlowC | im<<3 | rmidC<<6 | q<<9.
  // Per instruction a wave writes 8 rows x 128 B contiguous. Nontemporal:
  // never re-read on GPU.
#pragma unroll
  for (int i = 0; i < 32; ++i) {
    int row = rlowC + ((i & 7) << 3) + (rmidC << 6) + ((i >> 3) << 9);
    ntstore(&b4[(row << 12) + cb4 + c4], v[i]);
  }
}

extern "C" void kernel_launch(void* const* d_in, const int* in_sizes, int n_in,
                              void* d_out, int out_size, void* d_ws, size_t ws_size,
                              hipStream_t stream) {
  (void)in_sizes; (void)n_in; (void)d_ws; (void)ws_size; (void)out_size;
  const float* x = (const float*)d_in[0];
  float* out = (float*)d_out;
  // pass1: 2^25 / 2^14 = 2048 tiles
  wht_pass1<<<2048, 256, 0, stream>>>((const float4*)x, (float4*)out);
  // pass2: 2^12 f4-cols / 8 = 512 tiles, in-place on d_out
  wht_pass2<<<512, 512, 0, stream>>>((float4*)out);
}

// Round 5
// 296.608 us; speedup vs baseline: 1.6594x; 1.4086x over previous
//
#include <hip/hip_runtime.h>

// Walsh-Hadamard, N = 2^25 fp32. Two passes (stages commute):
//   pass1: bits 0..13 within contiguous 2^14 tiles
//          512 thr x 8 f4, 3 exchanges, 64 KiB LDS, 16 waves/CU
//   pass2: bits 14..24 = column transform of a (2048 x 2^14) matrix view
//          (round-0 kernel verbatim: 1024 thr x 16 f4, measured 84 us)

typedef float vf4 __attribute__((ext_vector_type(4)));

__device__ __forceinline__ float4 ntload(const float4* p) {
  vf4 r = __builtin_nontemporal_load(reinterpret_cast<const vf4*>(p));
  return *reinterpret_cast<float4*>(&r);
}

__device__ __forceinline__ void bfly(float4& a, float4& b) {
  float ax = a.x, ay = a.y, az = a.z, aw = a.w;
  a.x = ax + b.x; a.y = ay + b.y; a.z = az + b.z; a.w = aw + b.w;
  b.x = ax - b.x; b.y = ay - b.y; b.z = az - b.z; b.w = aw - b.w;
}

// 4 butterfly stages across the 4 index bits of v[16]
__device__ __forceinline__ void cross4(float4 (&v)[16]) {
#pragma unroll
  for (int m = 0; m < 4; ++m) {
#pragma unroll
    for (int k = 0; k < 16; ++k) {
      if (!(k & (1 << m))) bfly(v[k], v[k | (1 << m)]);
    }
  }
}

// 3 butterfly stages across the 3 index bits of v[8]
__device__ __forceinline__ void cross3(float4 (&v)[8]) {
#pragma unroll
  for (int m = 0; m < 3; ++m) {
#pragma unroll
    for (int k = 0; k < 8; ++k) {
      if (!(k & (1 << m))) bfly(v[k], v[k | (1 << m)]);
    }
  }
}

// ---------------- pass 1: bits 0..13 ----------------
// tile = 2^14 floats = 4096 f4; 512 threads x 8 float4; LDS 64 KiB.
// f4-index f[11:0]; element bits: e[1:0] in-f4, e = f*4+j.
// Schedule: in-f4 {e0,e1} | regs k = f[11:9] -> cross3 {e11..e13}
//   E1 -> regs f[2:0] -> cross3 {e2..e4}
//   E2 -> regs f[5:3] -> cross3 {e5..e7}
//   E3 -> regs f[8:6] -> cross3 {e8..e10}   (2+3+3+3+3 = 14 bits)
// Swizzle sigma(s) = s ^ ((s>>3)&7): every phase lands 8 lanes per 4-bank
// group (the wave64 b128 floor) -> conflict-free.
// "Write own read set" => only 3 barriers. Store = 1 KiB contiguous/wave.
__global__ __launch_bounds__(512) void wht_pass1(const float4* __restrict__ in4,
                                                 float4* __restrict__ out4) {
  __shared__ float4 lds[4096];  // 64 KiB
  const int t = threadIdx.x;
  const int base4 = (int)blockIdx.x << 12;  // tile base in float4s
  float4 v[8];
#pragma unroll
  for (int k = 0; k < 8; ++k)
    v[k] = ntload(&in4[base4 + t + (k << 9)]);
  // bits e0, e1 (inside each float4)
#pragma unroll
  for (int k = 0; k < 8; ++k) {
    float4 a = v[k];
    float s0 = a.x + a.y, d0 = a.x - a.y, s1 = a.z + a.w, d1 = a.z - a.w;
    v[k].x = s0 + s1; v[k].y = d0 + d1; v[k].z = s0 - s1; v[k].w = d0 - d1;
  }
  cross3(v);  // bits e11..e13 (k = f[11:9])

  // E1: canonical write f = t + k*512; read f = u + t*8 (regs -> f[2:0])
#pragma unroll
  for (int k = 0; k < 8; ++k) { int s = t + (k << 9); lds[s ^ ((s >> 3) & 7)] = v[k]; }
  __syncthreads();
#pragma unroll
  for (int u = 0; u < 8; ++u) { int s = u + (t << 3); v[u] = lds[s ^ ((s >> 3) & 7)]; }
  cross3(v);  // bits e2..e4

  // E2: write own E1-read slots (no barrier before writes)
#pragma unroll
  for (int u = 0; u < 8; ++u) { int s = u + (t << 3); lds[s ^ ((s >> 3) & 7)] = v[u]; }
  __syncthreads();
  {
    const int c0 = t & 7, c1 = t >> 3;  // f[2:0], f[11:6]
#pragma unroll
    for (int u = 0; u < 8; ++u) {
      int s = c0 + (u << 3) + (c1 << 6);
      v[u] = lds[s ^ ((s >> 3) & 7)];
    }
  }
  cross3(v);  // bits e5..e7

  // E3: write own E2-read slots
  {
    const int c0 = t & 7, c1 = t >> 3;
#pragma unroll
    for (int u = 0; u < 8; ++u) {
      int s = c0 + (u << 3) + (c1 << 6);
      lds[s ^ ((s >> 3) & 7)] = v[u];
    }
  }
  __syncthreads();
  const int c0b = t & 63, c1b = t >> 6;  // f[5:0], f[11:9]
#pragma unroll
  for (int u = 0; u < 8; ++u) {
    int s = c0b + (u << 6) + (c1b << 9);
    v[u] = lds[s ^ ((s >> 3) & 7)];
  }
  cross3(v);  // bits e8..e10

#pragma unroll
  for (int u = 0; u < 8; ++u) out4[base4 + c0b + (u << 6) + (c1b << 9)] = v[u];
}

// ---------------- pass 2: bits 14..24 ----------------
// Round-0 kernel verbatim (measured 84 us, VGPR 60, FETCH 66 MB, WRITE 140).
// rows r = idx>>14 (2048), cols = idx & 0x3fff. Tile = all rows x 32 cols.
// 1024 threads, 16 float4/thread. LDS = one column-quarter (2048 rows x 8
// cols = 64 KiB); exchanges run in 4 quarter-rounds gated by qt = (t>>1)&3.
// Quarter LDS index q = 2*r + (c4&1); swizzle L(q) = q ^ (((q>>8)&3)<<1).
__global__ __launch_bounds__(1024, 4) void wht_pass2(float4* __restrict__ b4) {
  __shared__ float4 lds[4096];  // 64 KiB
  const int t = threadIdx.x;
  const int cb4 = (int)blockIdx.x << 3;  // column base in float4s (32 cols)
  const int c4 = t & 7;                  // which float4 within 32-col segment
  const int cc = t & 1;                  // c4 bit 0
  const int qt = (t >> 1) & 3;           // c4 bits 1..2 = quarter id
  const int rlo = t >> 3;                // row bits 0..6 (load layout)
  float4 v[16];
#pragma unroll
  for (int k = 0; k < 16; ++k)
    v[k] = b4[((long)(rlo + (k << 7)) << 12) + cb4 + c4];
  cross4(v);  // row bits 7..10 (k)

  // exchange 1: A(rlo, k) -> B(rb = r[3:0] in regs, rhi = t>>3)
#pragma unroll 1
  for (int r4 = 0; r4 < 4; ++r4) {
    __syncthreads();
    if (qt == r4) {
#pragma unroll
      for (int k = 0; k < 16; ++k) {
        int q = ((rlo + (k << 7)) << 1) | cc;
        lds[q ^ (((q >> 8) & 3) << 1)] = v[k];
      }
    }
    __syncthreads();
    if (qt == r4) {
#pragma unroll
      for (int rb = 0; rb < 16; ++rb) {
        int q = ((rb + (rlo << 4)) << 1) | cc;
        v[rb] = lds[q ^ (((q >> 8) & 3) << 1)];
      }
    }
  }
  cross4(v);  // row bits 0..3 (rb)

  // exchange 2: B -> C. C-thread: rlowC = r[3:0], rhi4C = r[10:7],
  // holds rm = r[6:4] (8) x c (2 adjacent float4-cols in own quarter).
  const int rlowC = (t >> 3) & 15;
  const int rhi4C = (t & 1) | (((t >> 7) & 7) << 1);
#pragma unroll 1
  for (int r4 = 0; r4 < 4; ++r4) {
    __syncthreads();
    if (qt == r4) {  // B-write: same addresses this thread read in exchange 1
#pragma unroll
      for (int rb = 0; rb < 16; ++rb) {
        int q = ((rb + (rlo << 4)) << 1) | cc;
        lds[q ^ (((q >> 8) & 3) << 1)] = v[rb];
      }
    }
    __syncthreads();
    if (qt == r4) {
#pragma unroll
      for (int i = 0; i < 16; ++i) {
        int rm = i & 7, c = i >> 3;
        int r = rlowC + (rm << 4) + (rhi4C << 7);
        int q = (r << 1) | c;
        v[i] = lds[q ^ (((q >> 8) & 3) << 1)];
      }
    }
  }
  // row bits 4..6 (rm = low 3 bits of i; bit 3 of i is the column, untouched)
#pragma unroll
  for (int m = 0; m < 3; ++m) {
#pragma unroll
    for (int i = 0; i < 16; ++i) {
      if (!(i & (1 << m))) bfly(v[i], v[i | (1 << m)]);
    }
  }

#pragma unroll
  for (int i = 0; i < 16; ++i) {
    int rm = i & 7, c = i >> 3;
    int r = rlowC + (rm << 4) + (rhi4C << 7);
    b4[((long)r << 12) + cb4 + (qt << 1) + c] = v[i];
  }
}

extern "C" void kernel_launch(void* const* d_in, const int* in_sizes, int n_in,
                              void* d_out, int out_size, void* d_ws, size_t ws_size,
                              hipStream_t stream) {
  (void)in_sizes; (void)n_in; (void)d_ws; (void)ws_size; (void)out_size;
  const float* x = (const float*)d_in[0];
  float* out = (float*)d_out;
  // pass1: 2^25 / 2^14 = 2048 tiles
  wht_pass1<<<2048, 512, 0, stream>>>((const float4*)x, (float4*)out);
  // pass2: 2^14 cols / 32 = 512 tiles, in-place on d_out
  wht_pass2<<<512, 1024, 0, stream>>>((float4*)out);
}

// Round 6
// 273.228 us; speedup vs baseline: 1.8014x; 1.0856x over previous
//
#include <hip/hip_runtime.h>

// Walsh-Hadamard, N = 2^25 fp32. Two passes (stages commute):
//   pass1: bits 0..13 within contiguous 2^14 tiles (R5 kernel, unchanged)
//   pass2: bits 14..24 = column transform of a (2048 x 2^14) matrix view
// pass2 v2: 1024 thr x 16 f4 (VGPR-safe), 64 KiB LDS, exchange rounds keyed
// on row bits that are WAVE-uniform in both layouts -> every ds_b128 issues
// with all 64 lanes (R0 issued 4x more instrs at 1/4 lanes).

typedef float vf4 __attribute__((ext_vector_type(4)));

__device__ __forceinline__ float4 ntload(const float4* p) {
  vf4 r = __builtin_nontemporal_load(reinterpret_cast<const vf4*>(p));
  return *reinterpret_cast<float4*>(&r);
}
__device__ __forceinline__ void ntstore(float4* p, float4 v) {
  __builtin_nontemporal_store(*reinterpret_cast<vf4*>(&v),
                              reinterpret_cast<vf4*>(p));
}

__device__ __forceinline__ void bfly(float4& a, float4& b) {
  float ax = a.x, ay = a.y, az = a.z, aw = a.w;
  a.x = ax + b.x; a.y = ay + b.y; a.z = az + b.z; a.w = aw + b.w;
  b.x = ax - b.x; b.y = ay - b.y; b.z = az - b.z; b.w = aw - b.w;
}

__device__ __forceinline__ void cross4(float4 (&v)[16]) {
#pragma unroll
  for (int m = 0; m < 4; ++m) {
#pragma unroll
    for (int k = 0; k < 16; ++k) {
      if (!(k & (1 << m))) bfly(v[k], v[k | (1 << m)]);
    }
  }
}

__device__ __forceinline__ void cross3(float4 (&v)[8]) {
#pragma unroll
  for (int m = 0; m < 3; ++m) {
#pragma unroll
    for (int k = 0; k < 8; ++k) {
      if (!(k & (1 << m))) bfly(v[k], v[k | (1 << m)]);
    }
  }
}

// ---------------- pass 1: bits 0..13 ---------------- (R5, unchanged)
__global__ __launch_bounds__(512) void wht_pass1(const float4* __restrict__ in4,
                                                 float4* __restrict__ out4) {
  __shared__ float4 lds[4096];  // 64 KiB
  const int t = threadIdx.x;
  const int base4 = (int)blockIdx.x << 12;
  float4 v[8];
#pragma unroll
  for (int k = 0; k < 8; ++k)
    v[k] = ntload(&in4[base4 + t + (k << 9)]);
#pragma unroll
  for (int k = 0; k < 8; ++k) {
    float4 a = v[k];
    float s0 = a.x + a.y, d0 = a.x - a.y, s1 = a.z + a.w, d1 = a.z - a.w;
    v[k].x = s0 + s1; v[k].y = d0 + d1; v[k].z = s0 - s1; v[k].w = d0 - d1;
  }
  cross3(v);  // e11..e13

#pragma unroll
  for (int k = 0; k < 8; ++k) { int s = t + (k << 9); lds[s ^ ((s >> 3) & 7)] = v[k]; }
  __syncthreads();
#pragma unroll
  for (int u = 0; u < 8; ++u) { int s = u + (t << 3); v[u] = lds[s ^ ((s >> 3) & 7)]; }
  cross3(v);  // e2..e4

#pragma unroll
  for (int u = 0; u < 8; ++u) { int s = u + (t << 3); lds[s ^ ((s >> 3) & 7)] = v[u]; }
  __syncthreads();
  {
    const int c0 = t & 7, c1 = t >> 3;
#pragma unroll
    for (int u = 0; u < 8; ++u) {
      int s = c0 + (u << 3) + (c1 << 6);
      v[u] = lds[s ^ ((s >> 3) & 7)];
    }
  }
  cross3(v);  // e5..e7

  {
    const int c0 = t & 7, c1 = t >> 3;
#pragma unroll
    for (int u = 0; u < 8; ++u) {
      int s = c0 + (u << 3) + (c1 << 6);
      lds[s ^ ((s >> 3) & 7)] = v[u];
    }
  }
  __syncthreads();
  const int c0b = t & 63, c1b = t >> 6;
#pragma unroll
  for (int u = 0; u < 8; ++u) {
    int s = c0b + (u << 6) + (c1b << 9);
    v[u] = lds[s ^ ((s >> 3) & 7)];
  }
  cross3(v);  // e8..e10

#pragma unroll
  for (int u = 0; u < 8; ++u) out4[base4 + c0b + (u << 6) + (c1b << 9)] = v[u];
}

// ---------------- pass 2: bits 14..24 ----------------
// 2048 rows (r = idx>>14) x 2^12 f4-cols; block = 8 f4-cols (128-B row
// segments) x all rows; 1024 thr x 16 f4; LDS 64 KiB = one quarter-slice.
//
// Layouts (row bits r[10:0]; c4 = t[2:0] always):
//   A (load):  r[6:0]=t[9:3], regs k=r[10:7]            -> cross4 r[10:7]
//   B (mid):   r4=t[3], r[10:7]=t[7:4], r[6:5]=t[9:8], regs j=r[3:0]
//                                                       -> cross4 r[3:0]
//   C (store): r[2:0]=t[5:3], r[8:7]=t[9:8], r[10:9]=t[7:6],
//              regs i: i0=r3, i[3:1]=r[6:4]             -> cross3 r[6:4]
//
// E1 rounds keyed on Q1=r[6:5]: Q1 = t[9:8] in BOTH A and B -> in round q
// the 4 waves with t[9:8]==q write all 16 regs and read all 16 back,
// full-lane. E2 rounds keyed on Q2=r[10:9]: Q2 = t[7:6] in BOTH B and C
// (C chosen so each wave's write-round == read-round) -> same property.
// Peak live payload stays 16 f4 -> VGPR ~60, 2 blocks/CU.
//
// Slot map (bijective per round, 4096 f4 = 64 KiB):
//   E1: slot = c4 | r[2:0]<<3 | r4<<6 | r[8:7]<<7 | r9<<9 | r10<<10 | r3<<11
//   E2: slot = c4 | r[2:0]<<3 | r4<<6 | r[8:7]<<7 | r5<<9 | r6<<10 | r3<<11
// Writes in A and reads in C are 64-consecutive-slot (conflict-free);
// reads in B / writes in B are 8 runs of 8 -> even 8 lanes per bank window.
__global__ __launch_bounds__(1024, 4) void wht_pass2(float4* __restrict__ b4) {
  __shared__ float4 lds[4096];  // 64 KiB
  const int t = threadIdx.x;
  const int cb4 = (int)blockIdx.x << 3;
  const int c4 = t & 7;
  const int rA = t >> 3;            // layout A row bits r[6:0]
  const int g1 = (t >> 8) & 3;      // E1 group = r[6:5]
  const int g2 = (t >> 6) & 3;      // E2 group = r[10:9] (in B and C)
  float4 v[16];
#pragma unroll
  for (int k = 0; k < 16; ++k)
    v[k] = b4[((rA + (k << 7)) << 12) + cb4 + c4];  // plain: L3 hits on mid
  cross4(v);  // r[10:7]

  // E1: A -> B
  const int e1w = (t & 63) | (((t >> 7) & 1) << 6) | (((t >> 6) & 1) << 11);
  const int e1r = (t & 7) | (((t >> 3) & 1) << 6) | (((t >> 4) & 3) << 7) |
                  (((t >> 6) & 1) << 9) | (((t >> 7) & 1) << 10);
#pragma unroll 1
  for (int q = 0; q < 4; ++q) {
    if (q) __syncthreads();  // round q writes vs round q-1 reads
    if (g1 == q) {
#pragma unroll
      for (int k = 0; k < 16; ++k)
        lds[e1w | ((k & 3) << 7) | (((k >> 2) & 1) << 9) | ((k >> 3) << 10)] = v[k];
    }
    __syncthreads();
    if (g1 == q) {
#pragma unroll
      for (int j = 0; j < 16; ++j)
        v[j] = lds[e1r | ((j & 7) << 3) | ((j >> 3) << 11)];
    }
  }
  cross4(v);  // r[3:0]

  // E2: B -> C
  const int e2w = (t & 7) | (((t >> 3) & 1) << 6) | (((t >> 4) & 3) << 7) |
                  (((t >> 8) & 1) << 9) | (((t >> 9) & 1) << 10);
  const int e2r = (t & 63) | (((t >> 8) & 3) << 7);
#pragma unroll 1
  for (int q = 0; q < 4; ++q) {
    __syncthreads();  // round q writes vs prior reads (incl. E1 round 3)
    if (g2 == q) {
#pragma unroll
      for (int j = 0; j < 16; ++j)
        lds[e2w | ((j & 7) << 3) | ((j >> 3) << 11)] = v[j];
    }
    __syncthreads();
    if (g2 == q) {
#pragma unroll
      for (int i = 0; i < 16; ++i)
        v[i] = lds[e2r | (((i >> 1) & 1) << 6) | (((i >> 2) & 1) << 9) |
                   ((i >> 3) << 10) | ((i & 1) << 11)];
    }
  }
  // cross3 on r[6:4] = i[3:1]; i0 = r3 rides
#pragma unroll
  for (int m = 1; m < 4; ++m) {
#pragma unroll
    for (int i = 0; i < 16; ++i)
      if (!(i & (1 << m))) bfly(v[i], v[i | (1 << m)]);
  }

  // store: r = r[2:0] | r3<<3 | r[6:4]<<4 | r[8:7]<<7 | r[10:9]<<9
  // per instr: 8 rows x 128 B contiguous; nt: never re-read on GPU.
  const int rstore = ((t >> 3) & 7) | (((t >> 8) & 3) << 7) | (((t >> 6) & 3) << 9);
#pragma unroll
  for (int i = 0; i < 16; ++i) {
    int r = rstore | ((i & 1) << 3) | (((i >> 1) & 7) << 4);
    ntstore(&b4[(r << 12) + cb4 + c4], v[i]);
  }
}

extern "C" void kernel_launch(void* const* d_in, const int* in_sizes, int n_in,
                              void* d_out, int out_size, void* d_ws, size_t ws_size,
                              hipStream_t stream) {
  (void)in_sizes; (void)n_in; (void)d_ws; (void)ws_size; (void)out_size;
  const float* x = (const float*)d_in[0];
  float* out = (float*)d_out;
  // pass1: 2^25 / 2^14 = 2048 tiles
  wht_pass1<<<2048, 512, 0, stream>>>((const float4*)x, (float4*)out);
  // pass2: 2^12 f4-cols / 8 = 512 tiles, in-place on d_out
  wht_pass2<<<512, 1024, 0, stream>>>((float4*)out);
}